// Round 10
// baseline (886.390 us; speedup 1.0000x reference)
//
#include <hip/hip_runtime.h>

#define NN 50000
#define DD 128
#define EE 800000
#define SLOTS 64          // max degree cap (Poisson(16): P(deg>=65) ~ 1e-20/node)
#define CSTRIDE 16        // ints per counter -> one counter per 64B line
#define NSHARD 8          // shard count for the bucket pass (R19: single-pass atomics WORSE)
#define SHARD_NODES (NN / NSHARD)   // 6250

// prep virtual-block ranges (sharded bucket first: it's the long pole)
#define BKT_BLKS  6256    // 782 chunks x 8 shards
#define CVT_BLKS  6250    // NN*DD/4 float4s / 256
#define WCAT_BLKS 384
#define PB_VBLKS  (BKT_BLKS + CVT_BLKS + WCAT_BLKS + 1)

// 1563 blocks: residency-safe (capacity 2048 at (256,8): 64-VGPR cap, 4.6KB LDS; margin for
// harvested CUs) AND perfectly balanced layer loop (3125 tiles -> 2/block).
#define GRID_BLKS   1563
#define LAYER_TILES 3125  // 50000 / 16

typedef short bf16x8 __attribute__((ext_vector_type(8)));   // 8 bf16 = 4 VGPRs
typedef float f32x4  __attribute__((ext_vector_type(4)));

// ---- bf16 helpers (RNE) ----
__device__ __forceinline__ unsigned short f2bf(float f) {
    union { float f; unsigned u; } c; c.f = f;
    unsigned r = c.u + 0x7fffu + ((c.u >> 16) & 1u);
    return (unsigned short)(r >> 16);
}
__device__ __forceinline__ float bflo(unsigned p) { union { unsigned u; float f; } c; c.u = p << 16; return c.f; }
__device__ __forceinline__ float bfhi(unsigned p) { union { unsigned u; float f; } c; c.u = p & 0xffff0000u; return c.f; }
__device__ __forceinline__ unsigned packbf(float a, float b) { return (unsigned)f2bf(a) | ((unsigned)f2bf(b) << 16); }

struct MegaArgs {
    const int* src; const int* dst; const float* x;
    const float* W1l; const float* W1r; const float* W2l; const float* W2r;
    const float* W3l; const float* W3r;
    const float* b1; const float* b2; const float* b3;
    int* cntpad; unsigned* bar; unsigned short* eidx;
    unsigned short* xb; unsigned short* Bw;
    unsigned short* h1b; unsigned short* h2b; float* out;
};

// ---------------- software grid barrier (R20 post-mortem: cg grid.sync gave NONDETERMINISTIC
// garbage -> control passed but data didn't; per-XCD L2s need explicit agent-scope cache ops).
// Protocol: __syncthreads (drains ALL waves' stores to L2 -- compiler emits full waitcnt before
// s_barrier) -> t0: release fence (L2 writeback sc1) -> relaxed agent fetch_add -> relaxed spin
// (no per-poll invalidates) -> acquire fence (L1/L2 invalidate; runs on every CU via each
// block's t0) -> __syncthreads. One-shot counters, re-zeroed each launch by the memset.
__device__ __forceinline__ void gbar(unsigned* ctr) {
    __syncthreads();
    if (threadIdx.x == 0) {
        __threadfence();                  // agent release: drain + L2 writeback
        __hip_atomic_fetch_add(ctr, 1u, __ATOMIC_RELAXED, __HIP_MEMORY_SCOPE_AGENT);
        while (__hip_atomic_load(ctr, __ATOMIC_RELAXED, __HIP_MEMORY_SCOPE_AGENT) < GRID_BLKS)
            __builtin_amdgcn_s_sleep(8);
        __threadfence();                  // agent acquire: L1/L2 invalidate
    }
    __syncthreads();
}

// ---------------- prep virtual block: sharded bucket | x->bf16 | W concat | sentinel ----
__device__ __forceinline__ void prep_vblock(int b, int t, const MegaArgs& a) {
    if (b < BKT_BLKS) {
        const int shard = b & (NSHARD - 1);
        const int chunk = b >> 3;
        const int lo = shard * SHARD_NODES;
        const int hi = lo + SHARD_NODES;
        int i = (chunk * 256 + t) * 4;
        if (i + 3 < EE) {
            int4 dv = *(const int4*)(a.dst + i);
            int4 sv = *(const int4*)(a.src + i);
            if (dv.x >= lo && dv.x < hi) { int p = atomicAdd(&a.cntpad[dv.x * CSTRIDE], 1); if (p < SLOTS) a.eidx[dv.x * SLOTS + p] = (unsigned short)sv.x; }
            if (dv.y >= lo && dv.y < hi) { int p = atomicAdd(&a.cntpad[dv.y * CSTRIDE], 1); if (p < SLOTS) a.eidx[dv.y * SLOTS + p] = (unsigned short)sv.y; }
            if (dv.z >= lo && dv.z < hi) { int p = atomicAdd(&a.cntpad[dv.z * CSTRIDE], 1); if (p < SLOTS) a.eidx[dv.z * SLOTS + p] = (unsigned short)sv.z; }
            if (dv.w >= lo && dv.w < hi) { int p = atomicAdd(&a.cntpad[dv.w * CSTRIDE], 1); if (p < SLOTS) a.eidx[dv.w * SLOTS + p] = (unsigned short)sv.w; }
        } else {
            for (int e = i; e < EE; ++e) {
                int d = a.dst[e];
                if (d >= lo && d < hi) {
                    int p = atomicAdd(&a.cntpad[d * CSTRIDE], 1);
                    if (p < SLOTS) a.eidx[d * SLOTS + p] = (unsigned short)a.src[e];
                }
            }
        }
    } else if (b < BKT_BLKS + CVT_BLKS) {
        int i = (b - BKT_BLKS) * 256 + t;         // float4 index, exactly NN*DD/4
        float4 v = ((const float4*)a.x)[i];
        uint2 o;
        o.x = packbf(v.x, v.y);
        o.y = packbf(v.z, v.w);
        ((uint2*)a.xb)[i] = o;
    } else if (b < BKT_BLKS + CVT_BLKS + WCAT_BLKS) {
        int gid = (b - BKT_BLKS - CVT_BLKS) * 256 + t;   // 0..98303
        int layer = gid >> 15;
        int rem = gid & 32767;
        int c = rem >> 8;
        int k = rem & 255;
        const float* Wl = (layer == 0) ? a.W1l : (layer == 1) ? a.W2l : a.W3l;
        const float* Wr = (layer == 0) ? a.W1r : (layer == 1) ? a.W2r : a.W3r;
        float v = (k < 128) ? Wl[(size_t)c * DD + k] : Wr[(size_t)c * DD + (k - 128)];
        a.Bw[gid] = f2bf(v);
    } else {
        // zero sentinel row NN of xb/h1b/h2b: 3 rows x 256B = 48 uint4
        if (t < 48) {
            unsigned short* base = (t < 16) ? a.xb : (t < 32) ? a.h1b : a.h2b;
            ((uint4*)(base + (size_t)NN * DD))[t & 15] = make_uint4(0, 0, 0, 0);
        }
    }
}

// ---------------- fused layer stage (R14-proven structure + R18-proven cap-masking) ------
template <int RELU, int WRITE_F32>
__device__ __forceinline__ void layer_body(unsigned short (*sA)[136],
                                           const unsigned short* __restrict__ hb,
                                           const unsigned short* __restrict__ eidx,
                                           const int* __restrict__ cntpad,
                                           const unsigned short* Bw,
                                           const float* __restrict__ bias,
                                           float* __restrict__ outf,
                                           unsigned short* __restrict__ outb) {
    const int tid  = threadIdx.x;
    const int w    = tid >> 6;          // wave 0..3
    const int lane = tid & 63;
    const int sub  = lane >> 4;         // quarter 0..3 -> node within wave
    const int q    = lane & 15;         // 16B slot within the 256B row

    for (int tile = blockIdx.x; tile < LAYER_TILES; tile += GRID_BLKS) {
        const int row0 = tile * 16;

        // ---- Phase A: quarter-per-node gather, lane q owns channels 8q..8q+7 ----
        const int node = row0 + (w << 2) + sub;
        const int deg  = cntpad[node * CSTRIDE];
        uint2 mi = *(const uint2*)(eidx + (size_t)node * SLOTS + q * 4);
        const int cap = deg < SLOTS ? deg : SLOTS;     // quarter-uniform
        int cmax = cap;
        cmax = max(cmax, __shfl_xor(cmax, 16));
        cmax = max(cmax, __shfl_xor(cmax, 32));
        const int rounds = (cmax + 3) >> 2;            // wave-uniform, 0..16

        float a0 = 0.f, a1 = 0.f, a2 = 0.f, a3 = 0.f, a4 = 0.f, a5 = 0.f, a6 = 0.f, a7 = 0.f;
        for (int r = 0; r < rounds; ++r) {
            const int sl = (sub << 4) | r;             // source lane holding slots 4r..4r+3
            unsigned p0 = (unsigned)__shfl((int)mi.x, sl);
            unsigned p1 = (unsigned)__shfl((int)mi.y, sl);
            const int s0 = r << 2;
            unsigned i0 = (s0     < cap) ? (p0 & 0xffffu) : (unsigned)NN;
            unsigned i1 = (s0 + 1 < cap) ? (p0 >> 16)     : (unsigned)NN;
            unsigned i2 = (s0 + 2 < cap) ? (p1 & 0xffffu) : (unsigned)NN;
            unsigned i3 = (s0 + 3 < cap) ? (p1 >> 16)     : (unsigned)NN;
            uint4 v0 = ((const uint4*)(hb + (size_t)i0 * DD))[q];
            uint4 v1 = ((const uint4*)(hb + (size_t)i1 * DD))[q];
            uint4 v2 = ((const uint4*)(hb + (size_t)i2 * DD))[q];
            uint4 v3 = ((const uint4*)(hb + (size_t)i3 * DD))[q];
            a0 += (bflo(v0.x) + bflo(v1.x)) + (bflo(v2.x) + bflo(v3.x));
            a1 += (bfhi(v0.x) + bfhi(v1.x)) + (bfhi(v2.x) + bfhi(v3.x));
            a2 += (bflo(v0.y) + bflo(v1.y)) + (bflo(v2.y) + bflo(v3.y));
            a3 += (bfhi(v0.y) + bfhi(v1.y)) + (bfhi(v2.y) + bfhi(v3.y));
            a4 += (bflo(v0.z) + bflo(v1.z)) + (bflo(v2.z) + bflo(v3.z));
            a5 += (bfhi(v0.z) + bfhi(v1.z)) + (bfhi(v2.z) + bfhi(v3.z));
            a6 += (bflo(v0.w) + bflo(v1.w)) + (bflo(v2.w) + bflo(v3.w));
            a7 += (bfhi(v0.w) + bfhi(v1.w)) + (bfhi(v2.w) + bfhi(v3.w));
        }

        {
            const float inv = (deg > 0) ? (1.0f / (float)deg) : 0.f;
            uint4 o;
            o.x = packbf(a0 * inv, a1 * inv);
            o.y = packbf(a2 * inv, a3 * inv);
            o.z = packbf(a4 * inv, a5 * inv);
            o.w = packbf(a6 * inv, a7 * inv);
            *(uint4*)&sA[(w << 2) | sub][q * 8] = o;
        }
        __syncthreads();

        // ---- Phase B: MFMA dual-GEMM; wave w owns 32 cols ----
        const int m    = lane & 15;
        const int quad = lane >> 4;
        const int arow = row0 + m;

        // defeat LICM: B-fragments are tile-invariant; hoisting them = 64 VGPRs -> spill.
        const unsigned short* Bwt = Bw;
        asm volatile("" : "+s"(Bwt));

        f32x4 acc[2];
        acc[0] = (f32x4){0.f, 0.f, 0.f, 0.f};
        acc[1] = (f32x4){0.f, 0.f, 0.f, 0.f};

        const unsigned short* aptr = hb + (size_t)arow * DD + quad * 8;
#pragma unroll
        for (int ph = 0; ph < 2; ++ph) {
#pragma unroll
            for (int ks = 0; ks < 4; ++ks) {
                bf16x8 af;
                if (ph == 0) {
                    af = *(const bf16x8*)&sA[m][ks * 32 + quad * 8];
                } else {
                    af = *(const bf16x8*)(aptr + ks * 32);
                }
                const int koff = ph * 128 + ks * 32 + quad * 8;
#pragma unroll
                for (int ct = 0; ct < 2; ++ct) {
                    const int c = w * 32 + ct * 16 + m;
                    bf16x8 bfv = *(const bf16x8*)(Bwt + (size_t)c * 256 + koff);
                    acc[ct] = __builtin_amdgcn_mfma_f32_16x16x32_bf16(af, bfv, acc[ct], 0, 0, 0);
                }
            }
        }

#pragma unroll
        for (int ct = 0; ct < 2; ++ct) {
            const int gcol = w * 32 + ct * 16 + m;
            const float bv = bias[gcol];
#pragma unroll
            for (int r = 0; r < 4; ++r) {
                const int grow = row0 + quad * 4 + r;
                float v = acc[ct][r] + bv;
                if (RELU) v = fmaxf(v, 0.f);
                if (WRITE_F32) outf[(size_t)grow * DD + gcol] = v;
                else           outb[(size_t)grow * DD + gcol] = f2bf(v);
            }
        }
        __syncthreads();    // protect sA before next tile's Phase A store
    }
}

// ---------------- persistent mega-kernel: prep -> L1 -> L2 -> L3, software grid barrier ----
// R14-R18 budget: kernel sum ~212us vs wall ~283us -> ~60-70us inter-dispatch overhead.
// One plain launch (no cooperative machinery); residency guaranteed by capacity arithmetic.
__global__ __launch_bounds__(256, 8) void mega_kernel(MegaArgs a) {
    __shared__ __align__(16) unsigned short sA[16][136];

    for (int vb = blockIdx.x; vb < PB_VBLKS; vb += GRID_BLKS)
        prep_vblock(vb, threadIdx.x, a);
    gbar(a.bar + 0);

    layer_body<1, 0>(sA, a.xb,  a.eidx, a.cntpad, a.Bw,         a.b1, nullptr, a.h1b);
    gbar(a.bar + 16);
    layer_body<1, 0>(sA, a.h1b, a.eidx, a.cntpad, a.Bw + 32768, a.b2, nullptr, a.h2b);
    gbar(a.bar + 32);
    layer_body<0, 1>(sA, a.h2b, a.eidx, a.cntpad, a.Bw + 65536, a.b3, a.out, nullptr);
}

extern "C" void kernel_launch(void* const* d_in, const int* in_sizes, int n_in,
                              void* d_out, int out_size, void* d_ws, size_t ws_size,
                              hipStream_t stream) {
    const float* x    = (const float*)d_in[0];
    const int*   edge = (const int*)d_in[1];     // [2, E] int32
    const int*   srcp = edge;
    const int*   dstp = edge + EE;
    const float* W1l = (const float*)d_in[2];
    const float* b1  = (const float*)d_in[3];
    const float* W1r = (const float*)d_in[4];
    const float* W2l = (const float*)d_in[5];
    const float* b2  = (const float*)d_in[6];
    const float* W2r = (const float*)d_in[7];
    const float* W3l = (const float*)d_in[8];
    const float* b3  = (const float*)d_in[9];
    const float* W3r = (const float*)d_in[10];
    float* out = (float*)d_out;

    char* ws = (char*)d_ws;
    size_t off = 0;
    auto alloc = [&](size_t bytes) { void* p = ws + off; off += (bytes + 255) & ~(size_t)255; return p; };
    unsigned short* eidx   = (unsigned short*)alloc((size_t)NN * SLOTS * 2);      // 6.4 MB padded slots
    int*            cntpad = (int*)           alloc((size_t)NN * CSTRIDE * 4);    // 3.2 MB line-strided counters
    unsigned*       bar    = (unsigned*)      alloc(256);                         // 3 barrier counters (64B-strided)
    unsigned short* Bw     = (unsigned short*)alloc((size_t)3 * DD * 256 * 2);
    unsigned short* xb     = (unsigned short*)alloc((size_t)(NN + 1) * DD * 2);   // +1 zero row (sentinel NN)
    unsigned short* h1b    = (unsigned short*)alloc((size_t)(NN + 1) * DD * 2);
    unsigned short* h2b    = (unsigned short*)alloc((size_t)(NN + 1) * DD * 2);

    // one blitter memset covers cntpad (3.2MB) + barrier counters (contiguous next 256B)
    hipMemsetAsync(cntpad, 0, (size_t)NN * CSTRIDE * 4 + 256, stream);

    MegaArgs margs;
    margs.src = srcp; margs.dst = dstp; margs.x = x;
    margs.W1l = W1l; margs.W1r = W1r; margs.W2l = W2l; margs.W2r = W2r;
    margs.W3l = W3l; margs.W3r = W3r;
    margs.b1 = b1; margs.b2 = b2; margs.b3 = b3;
    margs.cntpad = cntpad; margs.bar = bar; margs.eidx = eidx;
    margs.xb = xb; margs.Bw = Bw; margs.h1b = h1b; margs.h2b = h2b; margs.out = out;

    mega_kernel<<<GRID_BLKS, 256, 0, stream>>>(margs);
}